// Round 13
// baseline (2496.629 us; speedup 1.0000x reference)
//
#include <hip/hip_runtime.h>
#include <stdint.h>

#define BATCH 32
#define SEQ   512
#define EDIM  512
#define HID   512            // per-direction hidden
#define NG    2048           // 4*HID gate rows
#define NTAG  16

typedef _Float16 f16;
typedef _Float16 f16x4 __attribute__((ext_vector_type(4)));
typedef _Float16 f16x8 __attribute__((ext_vector_type(8)));
typedef float    f32x4 __attribute__((ext_vector_type(4)));

#define LO_SCALE 2048.0f
#define LO_INV   (1.0f/2048.0f)

// ---------------- prep: fp32 -> f16 hi/lo limb split (4 matrices, 1 launch) -
__global__ __launch_bounds__(256) void k_split4(
    const float* __restrict__ s0, const float* __restrict__ s1,
    const float* __restrict__ s2, const float* __restrict__ s3,
    f16* __restrict__ wih_hi, f16* __restrict__ wih_lo,
    f16* __restrict__ whh_hi, f16* __restrict__ whh_lo) {
    const int y = blockIdx.y;
    const float* src = (y == 0) ? s0 : (y == 1) ? s1 : (y == 2) ? s2 : s3;
    f16* hi = ((y < 2) ? wih_hi : whh_hi) + (size_t)(y & 1) * NG * EDIM;
    f16* lo = ((y < 2) ? wih_lo : whh_lo) + (size_t)(y & 1) * NG * EDIM;
    int i = blockIdx.x * blockDim.x + threadIdx.x;
    int stride = gridDim.x * blockDim.x;
    for (; i < NG*EDIM; i += stride) {
        float x = src[i];
        f16 h = (f16)x;
        hi[i] = h;
        lo[i] = (f16)((x - (float)h) * LO_SCALE);
    }
}

// ---------------- gather embedding rows + split -----------------------------
__global__ __launch_bounds__(256) void k_gather(const int* __restrict__ sent,
                                                const float* __restrict__ emb,
                                                f16* __restrict__ ehi, f16* __restrict__ elo) {
    int m = blockIdx.x;                  // 0..16383 = b*SEQ+s
    int idx = sent[m];
    const float* src = emb + (size_t)idx * EDIM;
    int k = threadIdx.x * 2;
    float2 v = *(const float2*)(src + k);
    f16 h0 = (f16)v.x, h1 = (f16)v.y;
    ehi[(size_t)m*EDIM + k]     = h0;
    ehi[(size_t)m*EDIM + k + 1] = h1;
    elo[(size_t)m*EDIM + k]     = (f16)((v.x - (float)h0) * LO_SCALE);
    elo[(size_t)m*EDIM + k + 1] = (f16)((v.y - (float)h1) * LO_SCALE);
}

__device__ __forceinline__ void gld16(const void* g, void* l) {
    __builtin_amdgcn_global_load_lds((const __attribute__((address_space(1))) uint32_t*)g,
                                     (__attribute__((address_space(3))) uint32_t*)l, 16, 0, 0);
}
__device__ __forceinline__ f32x4 mfma16(f16x8 a, f16x8 b, f32x4 c) {
    return __builtin_amdgcn_mfma_f32_16x16x32_f16(a, b, c, 0, 0, 0);
}

// ---------------- persistent fused BiLSTM (v13 = v12 + kq wave tiling) ------
// 128 WGs: dir(2) x mt(2) x chunk(32, 16 units => 64 gate rows).
// MFMA phase retiled: waves = kq(8 K-eighths), each computing ALL 4 gates for
// its 64-unit K-slice -> A-plane LDS reads drop 4x (no cross-wave redundancy).
// Partials via gate-contiguous gbuf4[kq][row][u][g] (b128 write + b128 read).
// Everything else identical to v12 (proven 1900 us recurrence).
__global__ __launch_bounds__(512, 1) void k_rec(
    const f16* __restrict__ ehi,  const f16* __restrict__ elo,   // [16384][512]
    const f16* __restrict__ Whhi, const f16* __restrict__ Whlo,  // [2][2048][512]
    const f16* __restrict__ Wihi, const f16* __restrict__ Wilo,  // [2][2048][512]
    const float* __restrict__ b_f, const float* __restrict__ b_b,
    unsigned* __restrict__ hx,                                   // [2][2][32][512] packed
    float* __restrict__ h_hist)                                  // [16384][1024]
{
    __shared__ char  hhiS[16384];             // h   hi plane [16 rows][64 x 16B] swizzled
    __shared__ char  hloS[16384];             // h   lo plane
    __shared__ char  ehiS[16384];             // emb hi plane (same layout)
    __shared__ char  eloS[16384];             // emb lo plane
    __shared__ float gbuf4[8*16*16*4];        // [kq][row16][u16][g4] = 32 KiB

    const int wg    = blockIdx.x;
    const int dir   = wg >> 6;
    const int mt    = (wg >> 5) & 1;
    const int chunk = wg & 31;
    const int u0    = chunk * 16;
    const int tid   = threadIdx.x;
    const int lane  = tid & 63;
    const int wave  = tid >> 6;
    const int kq    = wave;            // K-eighth (64 f16 units)
    const int u     = lane & 15;
    const int q4    = lane >> 4;

    unsigned* hxd = hx + (size_t)dir * 2 * BATCH * HID;

    const int pbl = tid >> 4;          // cell: local batch row 0..15 (tid<256)
    const int pu  = tid & 15;          // cell: unit within chunk
    const char* hrowH = hhiS + u*1024; // A row = local batch row u
    const char* hrowL = hloS + u*1024;
    const char* erowH = ehiS + u*1024;
    const char* erowL = eloS + u*1024;
    const int u7 = u & 7;

    // step-invariant Whh + Wih B-fragments -> registers:
    // 4 gates x 2 kt x {Whh,Wih} x {hi,lo} = 32 f16x8 (128 VGPR)
    f16x8 bhv[4][2], blv[4][2], wbh[4][2], wbl[4][2];
    #pragma unroll
    for (int g = 0; g < 4; ++g) {
        const size_t row = (size_t)(dir*NG + g*512 + u0 + u) * EDIM;
        #pragma unroll
        for (int kt = 0; kt < 2; ++kt) {
            const int off = (kq*2 + kt)*32 + q4*8;
            bhv[g][kt] = *(const f16x8*)(Whhi + row + off);
            blv[g][kt] = *(const f16x8*)(Whlo + row + off);
            wbh[g][kt] = *(const f16x8*)(Wihi + row + off);
            wbl[g][kt] = *(const f16x8*)(Wilo + row + off);
        }
    }

    // per-cell bias (4 gates), loaded once
    float bv[4];
    {
        const float* bias = dir ? b_b : b_f;
        #pragma unroll
        for (int gg = 0; gg < 4; ++gg) bv[gg] = bias[gg*512 + u0 + pu];
    }

    // emb staging geometry: wave w fills plane row (o*8 + w), lane l fetches
    // logical unit (l ^ w) so the LDS write is linear (gld_lds constraint).
    const int grow0 = mt*16 + wave;            // o=0 source row (local +8 for o=1)
    const int srcu  = (lane ^ wave) * 8;       // f16 offset within source row

    float c = 0.0f;                   // cell state for (mt*16+pbl, u0+pu)

    for (int t = 0; t < SEQ; ++t) {
        const int s = dir ? (SEQ - 1 - t) : t;

        // ---- issue emb plane loads for step t (latency hides under poll) ----
        {
            size_t r0 = ((size_t)(grow0)*SEQ + s) * EDIM + srcu;
            size_t r1 = ((size_t)(grow0 + 8)*SEQ + s) * EDIM + srcu;
            gld16(ehi + r0, ehiS + tid*16);
            gld16(ehi + r1, ehiS + 8192 + tid*16);
            gld16(elo + r0, eloS + tid*16);
            gld16(elo + r1, eloS + 8192 + tid*16);
        }

        // ---- fill h planes: poll packed exchange data for this step's tag ----
        if (t == 0) {
            #pragma unroll
            for (int i = 0; i < 4; ++i) {
                int q = i*512 + tid, row = q >> 7, kqq = (q & 127)*4;
                int off = row*1024 + ((kqq >> 3) ^ (row & 7))*16 + (kqq & 4)*2;
                *(uint2*)(hhiS + off) = (uint2){0u, 0u};
                *(uint2*)(hloS + off) = (uint2){0u, 0u};
            }
        } else {
            const unsigned tag32 = ((unsigned)((t - 1) >> 1) & 3u) << 16;
            const unsigned* hsrc = hxd + (size_t)(t & 1)*BATCH*HID + (size_t)mt*16*HID;
            unsigned pend = 0xFu;
            while (pend) {
                unsigned long long va[4], vb[4];
                #pragma unroll
                for (int i = 0; i < 4; ++i) {
                    if (pend & (1u << i)) {
                        int q = i*512 + tid;
                        const unsigned long long* p =
                            (const unsigned long long*)(hsrc + (q >> 7)*HID + (q & 127)*4);
                        va[i] = __hip_atomic_load(p,     __ATOMIC_RELAXED, __HIP_MEMORY_SCOPE_AGENT);
                        vb[i] = __hip_atomic_load(p + 1, __ATOMIC_RELAXED, __HIP_MEMORY_SCOPE_AGENT);
                    }
                }
                #pragma unroll
                for (int i = 0; i < 4; ++i) {
                    if (!(pend & (1u << i))) continue;
                    unsigned w0 = (unsigned)va[i], w1 = (unsigned)(va[i] >> 32);
                    unsigned w2 = (unsigned)vb[i], w3 = (unsigned)(vb[i] >> 32);
                    if ((((w0 ^ tag32) | (w1 ^ tag32) | (w2 ^ tag32) | (w3 ^ tag32)) & 0x30000u) != 0u)
                        continue;   // not all words carry this step's tag yet
                    unsigned hi01 = (w0 & 0xffffu) | (w1 << 16);
                    unsigned hi23 = (w2 & 0xffffu) | (w3 << 16);
                    unsigned lo01 = (w0 >> 16) | (w1 & 0xffff0000u);
                    unsigned lo23 = (w2 >> 16) | (w3 & 0xffff0000u);
                    int q = i*512 + tid, row = q >> 7, kqq = (q & 127)*4;
                    int off = row*1024 + ((kqq >> 3) ^ (row & 7))*16 + (kqq & 4)*2;
                    *(uint2*)(hhiS + off) = (uint2){hi01, hi23};
                    *(uint2*)(hloS + off) = (uint2){lo01, lo23};
                    pend &= ~(1u << i);
                }
            }
        }
        __syncthreads();                 // h planes + emb planes (vmcnt 0) ready

        // ---- MFMA: this wave's K-eighth for ALL 4 gates ----
        f32x4 aH[4] = {}, aM1[4] = {}, aM2[4] = {};
        #pragma unroll
        for (int kt = 0; kt < 2; ++kt) {
            int off = (((kq*2 + kt)*4 + q4) ^ u7) * 16;
            f16x8 eh = *(const f16x8*)(erowH + off);
            f16x8 el = *(const f16x8*)(erowL + off);
            f16x8 ah = *(const f16x8*)(hrowH + off);
            f16x8 al = *(const f16x8*)(hrowL + off);
            #pragma unroll
            for (int g = 0; g < 4; ++g) {
                aH[g]  = mfma16(eh, wbh[g][kt], aH[g]);
                aM1[g] = mfma16(eh, wbl[g][kt], aM1[g]);
                aM2[g] = mfma16(el, wbh[g][kt], aM2[g]);
                aH[g]  = mfma16(ah, bhv[g][kt], aH[g]);
                aM1[g] = mfma16(ah, blv[g][kt], aM1[g]);
                aM2[g] = mfma16(al, bhv[g][kt], aM2[g]);
            }
        }
        #pragma unroll
        for (int j = 0; j < 4; ++j) {
            int row = q4*4 + j;                // local batch row
            f32x4 v;
            #pragma unroll
            for (int g = 0; g < 4; ++g)
                v[g] = aH[g][j] + (aM1[g][j] + aM2[g][j]) * LO_INV;
            *(f32x4*)(gbuf4 + ((kq*16 + row)*16 + u)*4) = v;
        }
        __syncthreads();                       // gbuf ready; plane reads done

        // ---- pointwise LSTM cell + packed tagged store ----
        if (tid < 256) {
            f32x4 sv = *(const f32x4*)(gbuf4 + ((0*16 + pbl)*16 + pu)*4);
            #pragma unroll
            for (int k2 = 1; k2 < 8; ++k2)
                sv += *(const f32x4*)(gbuf4 + ((k2*16 + pbl)*16 + pu)*4);
            float gi = sv[0] + bv[0];
            float gf = sv[1] + bv[1];
            float gg = sv[2] + bv[2];
            float go = sv[3] + bv[3];
            float si = 1.0f / (1.0f + __expf(-gi));
            float sf = 1.0f / (1.0f + __expf(-gf));
            float tg = 1.0f - 2.0f / (__expf(2.0f*gg) + 1.0f);
            float so = 1.0f / (1.0f + __expf(-go));
            c = sf * c + si * tg;
            float hval = so * (1.0f - 2.0f / (__expf(2.0f*c) + 1.0f));
            f16 hh = (f16)hval;
            f16 hl = (f16)((hval - (float)hh) * LO_SCALE);
            unsigned packed = (unsigned)__builtin_bit_cast(unsigned short, hh)
                            | ((unsigned)__builtin_bit_cast(unsigned short, hl) << 16);
            packed = (packed & ~0x30000u) | ((((unsigned)t >> 1) & 3u) << 16);
            int b = mt*16 + pbl;
            unsigned* hdst = hxd + (size_t)((t + 1) & 1)*BATCH*HID + b*HID + u0 + pu;
            __hip_atomic_store(hdst, packed, __ATOMIC_RELAXED, __HIP_MEMORY_SCOPE_AGENT);
            // h_hist off the critical path; non-temporal (keep L2 clean)
            __builtin_nontemporal_store(hval,
                h_hist + ((size_t)b*SEQ + s)*1024 + dir*HID + u0 + pu);
        }
    }
}

// ---------------- output projection: feats = H @ W_out^T + b_out ------------
__global__ __launch_bounds__(256) void k_feats(
    const float* __restrict__ H,      // [16384][1024]
    const float* __restrict__ Wout,   // [16][1024]
    const float* __restrict__ bout,   // [16]
    float* __restrict__ feats)        // [16384][16]
{
    __shared__ float Wt[1024][16];    // 64 KiB, transposed
    int tid = threadIdx.x;
    for (int i = tid; i < 16384; i += 256)
        Wt[i & 1023][i >> 10] = Wout[i];   // coalesced global read
    __syncthreads();
    int wave = tid >> 6, lane = tid & 63;
    int row = blockIdx.x * 4 + wave;
    const float* hrow = H + (size_t)row * 1024;
    float acc[16];
    #pragma unroll
    for (int t = 0; t < 16; ++t) acc[t] = 0.f;
    #pragma unroll
    for (int cc = 0; cc < 4; ++cc) {
        float4 hv = *(const float4*)(hrow + cc*256 + lane*4);
        #pragma unroll
        for (int j = 0; j < 4; ++j) {
            int k = cc*256 + lane*4 + j;
            float h = (&hv.x)[j];
            #pragma unroll
            for (int tg = 0; tg < 16; ++tg) acc[tg] += h * Wt[k][tg];
        }
    }
    #pragma unroll
    for (int off = 32; off >= 1; off >>= 1) {
        #pragma unroll
        for (int tg = 0; tg < 16; ++tg) acc[tg] += __shfl_xor(acc[tg], off);
    }
    if (lane == 0) {
        #pragma unroll
        for (int tg = 0; tg < 16; ++tg)
            feats[(size_t)row*16 + tg] = acc[tg] + bout[tg];
    }
}

// ---------------- Viterbi + backtrace (one wave per batch, LDS-staged) ------
__global__ __launch_bounds__(64) void k_viterbi(
    const float* __restrict__ feats,   // [32][512][16]
    const float* __restrict__ trans,   // [16][16] trans[prev][cur]
    const float* __restrict__ startt, const float* __restrict__ stopt,
    int* __restrict__ out)             // [32][512]
{
    __shared__ float fs[SEQ*NTAG];     // 32 KiB: whole feats row
    __shared__ unsigned char bp[511*16];
    int b = blockIdx.x;
    int lane = threadIdx.x;
    // stage feats row into LDS (coalesced float4)
    {
        const float4* src = (const float4*)(feats + (size_t)b * SEQ * NTAG);
        float4* dst = (float4*)fs;
        for (int i = lane; i < SEQ*NTAG/4; i += 64) dst[i] = src[i];
    }
    int cur = lane & 15;
    int q   = lane >> 4;
    float tr[4];
    #pragma unroll
    for (int i = 0; i < 4; ++i) tr[i] = trans[(q*4 + i)*16 + cur];
    __syncthreads();
    float v = fs[cur] + startt[cur];
    for (int s = 1; s < SEQ; ++s) {
        float best = -1e30f; int bi = 0;
        #pragma unroll
        for (int i = 0; i < 4; ++i) {
            float pv = __shfl(v, q*4 + i);
            float sc = pv + tr[i];
            if (sc > best) { best = sc; bi = q*4 + i; }   // first-max within quarter
        }
        #pragma unroll
        for (int off = 16; off <= 32; off <<= 1) {
            float ob = __shfl_xor(best, off);
            int   oi = __shfl_xor(bi, off);
            if (ob > best || (ob == best && oi < bi)) { best = ob; bi = oi; }
        }
        if (lane < 16) bp[(s - 1)*16 + cur] = (unsigned char)bi;
        v = best + fs[s*16 + cur];
    }
    float sc = v + stopt[cur];
    int bc = cur;
    #pragma unroll
    for (int off = 1; off <= 32; off <<= 1) {
        float os = __shfl_xor(sc, off);
        int   oc = __shfl_xor(bc, off);
        if (os > sc || (os == sc && oc < bc)) { sc = os; bc = oc; }
    }
    __syncthreads();
    if (lane == 0) {
        int curt = bc;
        out[b*SEQ + SEQ - 1] = curt;
        for (int s2 = SEQ - 2; s2 >= 0; --s2) {
            curt = bp[s2*16 + curt];
            out[b*SEQ + s2] = curt;
        }
    }
}

// ---------------- launch ----------------------------------------------------
extern "C" void kernel_launch(void* const* d_in, const int* in_sizes, int n_in,
                              void* d_out, int out_size, void* d_ws, size_t ws_size,
                              hipStream_t stream) {
    (void)in_sizes; (void)n_in; (void)out_size; (void)ws_size;
    const int*   sentence  = (const int*)  d_in[0];
    const float* embedding = (const float*)d_in[1];
    const float* Wih_f = (const float*)d_in[2];
    const float* Whh_f = (const float*)d_in[3];
    const float* b_f   = (const float*)d_in[4];
    const float* Wih_b = (const float*)d_in[5];
    const float* Whh_b = (const float*)d_in[6];
    const float* b_b   = (const float*)d_in[7];
    const float* W_out = (const float*)d_in[8];
    const float* b_out = (const float*)d_in[9];
    const float* trans = (const float*)d_in[10];
    const float* startt= (const float*)d_in[11];
    const float* stopt = (const float*)d_in[12];

    char* ws = (char*)d_ws;
    float* h_hist = (float*)(ws);                           //  67,108,864 B  [16384][1024]
    f16*   ehi    = (f16*)  (ws +  67108864ull);            //  16,777,216 B
    f16*   elo    = (f16*)  (ws +  83886080ull);            //  16,777,216 B
    f16*   wihhi  = (f16*)  (ws + 100663296ull);            //   4,194,304 B
    f16*   wihlo  = (f16*)  (ws + 104857600ull);
    f16*   whhhi  = (f16*)  (ws + 109051904ull);
    f16*   whhlo  = (f16*)  (ws + 113246208ull);
    unsigned* hx  = (unsigned*)(ws + 117440512ull);         //     262,144 B  [2][2][32][512]
    float* feats  = (float*)(ws + 117702656ull);            //   1,048,576 B

    // init exchange buffers: tag field (bits 17:16) = 3
    hipMemsetAsync(hx, 0xFF, 262144, stream);

    k_split4<<<dim3(512, 4), 256, 0, stream>>>(Wih_f, Wih_b, Whh_f, Whh_b,
                                               wihhi, wihlo, whhhi, whhlo);
    k_gather<<<16384, 256, 0, stream>>>(sentence, embedding, ehi, elo);

    k_rec<<<128, 512, 0, stream>>>(ehi, elo, whhhi, whhlo, wihhi, wihlo,
                                   b_f, b_b, hx, h_hist);

    k_feats<<<4096, 256, 0, stream>>>(h_hist, W_out, b_out, feats);
    k_viterbi<<<32, 64, 0, stream>>>(feats, trans, startt, stopt, (int*)d_out);
}

// Round 14
// 2075.190 us; speedup vs baseline: 1.2031x; 1.2031x over previous
//
#include <hip/hip_runtime.h>
#include <stdint.h>

#define BATCH 32
#define SEQ   512
#define EDIM  512
#define HID   512            // per-direction hidden
#define NG    2048           // 4*HID gate rows
#define NTAG  16

typedef _Float16 f16;
typedef _Float16 f16x4 __attribute__((ext_vector_type(4)));
typedef _Float16 f16x8 __attribute__((ext_vector_type(8)));
typedef float    f32x4 __attribute__((ext_vector_type(4)));

#define LO_SCALE 2048.0f
#define LO_INV   (1.0f/2048.0f)

// ---------------- prep: fp32 -> f16 hi/lo limb split (4 matrices, 1 launch) -
__global__ __launch_bounds__(256) void k_split4(
    const float* __restrict__ s0, const float* __restrict__ s1,
    const float* __restrict__ s2, const float* __restrict__ s3,
    f16* __restrict__ wih_hi, f16* __restrict__ wih_lo,
    f16* __restrict__ whh_hi, f16* __restrict__ whh_lo) {
    const int y = blockIdx.y;
    const float* src = (y == 0) ? s0 : (y == 1) ? s1 : (y == 2) ? s2 : s3;
    f16* hi = ((y < 2) ? wih_hi : whh_hi) + (size_t)(y & 1) * NG * EDIM;
    f16* lo = ((y < 2) ? wih_lo : whh_lo) + (size_t)(y & 1) * NG * EDIM;
    int i = blockIdx.x * blockDim.x + threadIdx.x;
    int stride = gridDim.x * blockDim.x;
    for (; i < NG*EDIM; i += stride) {
        float x = src[i];
        f16 h = (f16)x;
        hi[i] = h;
        lo[i] = (f16)((x - (float)h) * LO_SCALE);
    }
}

// ---------------- gather embedding rows + split -----------------------------
__global__ __launch_bounds__(256) void k_gather(const int* __restrict__ sent,
                                                const float* __restrict__ emb,
                                                f16* __restrict__ ehi, f16* __restrict__ elo) {
    int m = blockIdx.x;                  // 0..16383 = b*SEQ+s
    int idx = sent[m];
    const float* src = emb + (size_t)idx * EDIM;
    int k = threadIdx.x * 2;
    float2 v = *(const float2*)(src + k);
    f16 h0 = (f16)v.x, h1 = (f16)v.y;
    ehi[(size_t)m*EDIM + k]     = h0;
    ehi[(size_t)m*EDIM + k + 1] = h1;
    elo[(size_t)m*EDIM + k]     = (f16)((v.x - (float)h0) * LO_SCALE);
    elo[(size_t)m*EDIM + k + 1] = (f16)((v.y - (float)h1) * LO_SCALE);
}

__device__ __forceinline__ void gld16(const void* g, void* l) {
    __builtin_amdgcn_global_load_lds((const __attribute__((address_space(1))) uint32_t*)g,
                                     (__attribute__((address_space(3))) uint32_t*)l, 16, 0, 0);
}
__device__ __forceinline__ f32x4 mfma16(f16x8 a, f16x8 b, f32x4 c) {
    return __builtin_amdgcn_mfma_f32_16x16x32_f16(a, b, c, 0, 0, 0);
}

// ---------------- persistent fused BiLSTM (v14 = v12 @ 256 WGs) -------------
// 256 WGs: dir(2) x mq(4, batch quarter = 8 rows) x chunk(32, 16 units).
// Identical phase structure / tag protocol / swizzle to v12 (proven 1900us),
// with per-WG batch rows halved 16->8: poll, fill, emb staging, and cell all
// halve; MFMA M=16 runs with row-duplication (A row = u&7) - MFMA is ~9%
// busy so the waste is free. Waves = (g 4 x kh 2), B-fragments in registers.
__global__ __launch_bounds__(512, 1) void k_rec(
    const f16* __restrict__ ehi,  const f16* __restrict__ elo,   // [16384][512]
    const f16* __restrict__ Whhi, const f16* __restrict__ Whlo,  // [2][2048][512]
    const f16* __restrict__ Wihi, const f16* __restrict__ Wilo,  // [2][2048][512]
    const float* __restrict__ b_f, const float* __restrict__ b_b,
    unsigned* __restrict__ hx,                                   // [2][2][32][512] packed
    float* __restrict__ h_hist)                                  // [16384][1024]
{
    __shared__ char  hhiS[8192];              // h   hi plane [8 rows][64 x 16B] swizzled
    __shared__ char  hloS[8192];              // h   lo plane
    __shared__ char  ehiS[8192];              // emb hi plane (same layout)
    __shared__ char  eloS[8192];              // emb lo plane
    __shared__ float gbuf[2*4*16*17];         // [kh][g][row16][17] (rows 8-15 dup)

    const int wg    = blockIdx.x;
    const int dir   = wg >> 7;
    const int mq    = (wg >> 5) & 3;   // batch quarter
    const int chunk = wg & 31;
    const int u0    = chunk * 16;
    const int b0    = mq * 8;
    const int tid   = threadIdx.x;
    const int lane  = tid & 63;
    const int wave  = tid >> 6;
    const int g     = wave & 3;        // gate type
    const int kh    = wave >> 2;       // K half
    const int u     = lane & 15;
    const int q4    = lane >> 4;

    unsigned* hxd = hx + (size_t)dir * 2 * BATCH * HID;

    const int pbl = tid >> 4;          // cell: local batch row 0..7 (tid<128)
    const int pu  = tid & 15;          // cell: unit within chunk
    const char* hrowH = hhiS + (u & 7)*1024;   // A row = local batch row (u&7)
    const char* hrowL = hloS + (u & 7)*1024;
    const char* erowH = ehiS + (u & 7)*1024;
    const char* erowL = eloS + (u & 7)*1024;
    const int u7 = u & 7;

    // step-invariant Whh + Wih B-fragments -> registers (8 kt x hi/lo each)
    f16x8 bhv[8], blv[8], wbh[8], wbl[8];
    {
        const size_t row = (size_t)(dir*NG + g*512 + u0 + u) * EDIM;
        const f16* ph = Whhi + row + q4*8;
        const f16* pl = Whlo + row + q4*8;
        const f16* qh = Wihi + row + q4*8;
        const f16* ql = Wilo + row + q4*8;
        #pragma unroll
        for (int kt = 0; kt < 8; ++kt) {
            bhv[kt] = *(const f16x8*)(ph + (kh*8 + kt)*32);
            blv[kt] = *(const f16x8*)(pl + (kh*8 + kt)*32);
            wbh[kt] = *(const f16x8*)(qh + (kh*8 + kt)*32);
            wbl[kt] = *(const f16x8*)(ql + (kh*8 + kt)*32);
        }
    }

    // per-cell bias (4 gates), loaded once
    float bv[4];
    {
        const float* bias = dir ? b_b : b_f;
        #pragma unroll
        for (int gg = 0; gg < 4; ++gg) bv[gg] = bias[gg*512 + u0 + pu];
    }

    // emb staging: wave w fills plane row w (8 rows); lane l fetches logical
    // unit (l ^ w) so the LDS write is linear (gld_lds constraint).
    const int grow = b0 + wave;                // global batch row for this wave
    const int srcu = (lane ^ wave) * 8;        // f16 offset within source row

    float c = 0.0f;                   // cell state for (b0+pbl, u0+pu)

    for (int t = 0; t < SEQ; ++t) {
        const int s = dir ? (SEQ - 1 - t) : t;

        // ---- issue emb plane loads for step t (latency hides under poll) ----
        {
            size_t r0 = ((size_t)grow*SEQ + s) * EDIM + srcu;
            gld16(ehi + r0, ehiS + tid*16);
            gld16(elo + r0, eloS + tid*16);
        }

        // ---- fill h planes: poll packed exchange data for this step's tag ----
        if (t == 0) {
            #pragma unroll
            for (int i = 0; i < 2; ++i) {
                int q = i*512 + tid, row = q >> 7, kqq = (q & 127)*4;
                int off = row*1024 + ((kqq >> 3) ^ row)*16 + (kqq & 4)*2;
                *(uint2*)(hhiS + off) = (uint2){0u, 0u};
                *(uint2*)(hloS + off) = (uint2){0u, 0u};
            }
        } else {
            const unsigned tag32 = ((unsigned)((t - 1) >> 1) & 3u) << 16;
            const unsigned* hsrc = hxd + (size_t)(t & 1)*BATCH*HID + (size_t)b0*HID;
            unsigned pend = 0x3u;
            while (pend) {
                unsigned long long va[2], vb[2];
                #pragma unroll
                for (int i = 0; i < 2; ++i) {
                    if (pend & (1u << i)) {
                        int q = i*512 + tid;
                        const unsigned long long* p =
                            (const unsigned long long*)(hsrc + (q >> 7)*HID + (q & 127)*4);
                        va[i] = __hip_atomic_load(p,     __ATOMIC_RELAXED, __HIP_MEMORY_SCOPE_AGENT);
                        vb[i] = __hip_atomic_load(p + 1, __ATOMIC_RELAXED, __HIP_MEMORY_SCOPE_AGENT);
                    }
                }
                #pragma unroll
                for (int i = 0; i < 2; ++i) {
                    if (!(pend & (1u << i))) continue;
                    unsigned w0 = (unsigned)va[i], w1 = (unsigned)(va[i] >> 32);
                    unsigned w2 = (unsigned)vb[i], w3 = (unsigned)(vb[i] >> 32);
                    if ((((w0 ^ tag32) | (w1 ^ tag32) | (w2 ^ tag32) | (w3 ^ tag32)) & 0x30000u) != 0u)
                        continue;   // not all words carry this step's tag yet
                    unsigned hi01 = (w0 & 0xffffu) | (w1 << 16);
                    unsigned hi23 = (w2 & 0xffffu) | (w3 << 16);
                    unsigned lo01 = (w0 >> 16) | (w1 & 0xffff0000u);
                    unsigned lo23 = (w2 >> 16) | (w3 & 0xffff0000u);
                    int q = i*512 + tid, row = q >> 7, kqq = (q & 127)*4;
                    int off = row*1024 + ((kqq >> 3) ^ row)*16 + (kqq & 4)*2;
                    *(uint2*)(hhiS + off) = (uint2){hi01, hi23};
                    *(uint2*)(hloS + off) = (uint2){lo01, lo23};
                    pend &= ~(1u << i);
                }
            }
        }
        __syncthreads();                 // h planes + emb planes (vmcnt 0) ready

        // ---- MFMA: gates = emb@Wih + h@Whh for this wave's (g, kh) ----
        f32x4 aH = {0.f,0.f,0.f,0.f}, aM1 = aH, aM2 = aH;
        #pragma unroll
        for (int kt = 0; kt < 8; ++kt) {
            int off = (((kh*8 + kt)*4 + q4) ^ u7) * 16;
            f16x8 eh = *(const f16x8*)(erowH + off);
            f16x8 el = *(const f16x8*)(erowL + off);
            f16x8 ah = *(const f16x8*)(hrowH + off);
            f16x8 al = *(const f16x8*)(hrowL + off);
            aH  = mfma16(eh, wbh[kt], aH);
            aM1 = mfma16(eh, wbl[kt], aM1);
            aM2 = mfma16(el, wbh[kt], aM2);
            aH  = mfma16(ah, bhv[kt], aH);
            aM1 = mfma16(ah, blv[kt], aM1);
            aM2 = mfma16(al, bhv[kt], aM2);
        }
        #pragma unroll
        for (int j = 0; j < 4; ++j) {
            int row = q4*4 + j;                // 0..15 (rows 8-15 duplicate 0-7)
            gbuf[(kh*4 + g)*272 + row*17 + u] = aH[j] + (aM1[j] + aM2[j]) * LO_INV;
        }
        __syncthreads();                       // gbuf ready; plane reads done

        // ---- pointwise LSTM cell + packed tagged store (8 rows x 16 units) ----
        if (tid < 128) {
            float gs[4];
            #pragma unroll
            for (int gg = 0; gg < 4; ++gg)
                gs[gg] = gbuf[(0*4 + gg)*272 + pbl*17 + pu]
                       + gbuf[(1*4 + gg)*272 + pbl*17 + pu] + bv[gg];
            float si = 1.0f / (1.0f + __expf(-gs[0]));
            float sf = 1.0f / (1.0f + __expf(-gs[1]));
            float tg = 1.0f - 2.0f / (__expf(2.0f*gs[2]) + 1.0f);
            float so = 1.0f / (1.0f + __expf(-gs[3]));
            c = sf * c + si * tg;
            float hval = so * (1.0f - 2.0f / (__expf(2.0f*c) + 1.0f));
            f16 hh = (f16)hval;
            f16 hl = (f16)((hval - (float)hh) * LO_SCALE);
            unsigned packed = (unsigned)__builtin_bit_cast(unsigned short, hh)
                            | ((unsigned)__builtin_bit_cast(unsigned short, hl) << 16);
            packed = (packed & ~0x30000u) | ((((unsigned)t >> 1) & 3u) << 16);
            int b = b0 + pbl;
            unsigned* hdst = hxd + (size_t)((t + 1) & 1)*BATCH*HID + b*HID + u0 + pu;
            __hip_atomic_store(hdst, packed, __ATOMIC_RELAXED, __HIP_MEMORY_SCOPE_AGENT);
            // h_hist off the critical path; non-temporal (keep L2 clean)
            __builtin_nontemporal_store(hval,
                h_hist + ((size_t)b*SEQ + s)*1024 + dir*HID + u0 + pu);
        }
    }
}

// ---------------- output projection: feats = H @ W_out^T + b_out ------------
// 256 blocks x 64 rows: Wout LDS staging amortized 16x vs 4096-block version.
__global__ __launch_bounds__(256) void k_feats(
    const float* __restrict__ H,      // [16384][1024]
    const float* __restrict__ Wout,   // [16][1024]
    const float* __restrict__ bout,   // [16]
    float* __restrict__ feats)        // [16384][16]
{
    __shared__ float Wt[1024][16];    // 64 KiB, transposed
    int tid = threadIdx.x;
    for (int i = tid; i < 16384; i += 256)
        Wt[i & 1023][i >> 10] = Wout[i];   // coalesced global read
    __syncthreads();
    int wave = tid >> 6, lane = tid & 63;
    float bo[16];
    #pragma unroll
    for (int tg = 0; tg < 16; ++tg) bo[tg] = bout[tg];
    for (int r = 0; r < 16; ++r) {
        int row = blockIdx.x * 64 + wave * 16 + r;
        const float* hrow = H + (size_t)row * 1024;
        float acc[16];
        #pragma unroll
        for (int t = 0; t < 16; ++t) acc[t] = 0.f;
        #pragma unroll
        for (int cc = 0; cc < 4; ++cc) {
            float4 hv = *(const float4*)(hrow + cc*256 + lane*4);
            #pragma unroll
            for (int j = 0; j < 4; ++j) {
                int k = cc*256 + lane*4 + j;
                float h = (&hv.x)[j];
                #pragma unroll
                for (int tg = 0; tg < 16; ++tg) acc[tg] += h * Wt[k][tg];
            }
        }
        #pragma unroll
        for (int off = 32; off >= 1; off >>= 1) {
            #pragma unroll
            for (int tg = 0; tg < 16; ++tg) acc[tg] += __shfl_xor(acc[tg], off);
        }
        if (lane == 0) {
            #pragma unroll
            for (int tg = 0; tg < 16; ++tg)
                feats[(size_t)row*16 + tg] = acc[tg] + bo[tg];
        }
    }
}

// ---------------- Viterbi + backtrace (one wave per batch, LDS-staged) ------
__global__ __launch_bounds__(64) void k_viterbi(
    const float* __restrict__ feats,   // [32][512][16]
    const float* __restrict__ trans,   // [16][16] trans[prev][cur]
    const float* __restrict__ startt, const float* __restrict__ stopt,
    int* __restrict__ out)             // [32][512]
{
    __shared__ float fs[SEQ*NTAG];     // 32 KiB: whole feats row
    __shared__ unsigned char bp[511*16];
    int b = blockIdx.x;
    int lane = threadIdx.x;
    // stage feats row into LDS (coalesced float4)
    {
        const float4* src = (const float4*)(feats + (size_t)b * SEQ * NTAG);
        float4* dst = (float4*)fs;
        for (int i = lane; i < SEQ*NTAG/4; i += 64) dst[i] = src[i];
    }
    int cur = lane & 15;
    int q   = lane >> 4;
    float tr[4];
    #pragma unroll
    for (int i = 0; i < 4; ++i) tr[i] = trans[(q*4 + i)*16 + cur];
    __syncthreads();
    float v = fs[cur] + startt[cur];
    for (int s = 1; s < SEQ; ++s) {
        float best = -1e30f; int bi = 0;
        #pragma unroll
        for (int i = 0; i < 4; ++i) {
            float pv = __shfl(v, q*4 + i);
            float sc = pv + tr[i];
            if (sc > best) { best = sc; bi = q*4 + i; }   // first-max within quarter
        }
        #pragma unroll
        for (int off = 16; off <= 32; off <<= 1) {
            float ob = __shfl_xor(best, off);
            int   oi = __shfl_xor(bi, off);
            if (ob > best || (ob == best && oi < bi)) { best = ob; bi = oi; }
        }
        if (lane < 16) bp[(s - 1)*16 + cur] = (unsigned char)bi;
        v = best + fs[s*16 + cur];
    }
    float sc = v + stopt[cur];
    int bc = cur;
    #pragma unroll
    for (int off = 1; off <= 32; off <<= 1) {
        float os = __shfl_xor(sc, off);
        int   oc = __shfl_xor(bc, off);
        if (os > sc || (os == sc && oc < bc)) { sc = os; bc = oc; }
    }
    __syncthreads();
    if (lane == 0) {
        int curt = bc;
        out[b*SEQ + SEQ - 1] = curt;
        for (int s2 = SEQ - 2; s2 >= 0; --s2) {
            curt = bp[s2*16 + curt];
            out[b*SEQ + s2] = curt;
        }
    }
}

// ---------------- launch ----------------------------------------------------
extern "C" void kernel_launch(void* const* d_in, const int* in_sizes, int n_in,
                              void* d_out, int out_size, void* d_ws, size_t ws_size,
                              hipStream_t stream) {
    (void)in_sizes; (void)n_in; (void)out_size; (void)ws_size;
    const int*   sentence  = (const int*)  d_in[0];
    const float* embedding = (const float*)d_in[1];
    const float* Wih_f = (const float*)d_in[2];
    const float* Whh_f = (const float*)d_in[3];
    const float* b_f   = (const float*)d_in[4];
    const float* Wih_b = (const float*)d_in[5];
    const float* Whh_b = (const float*)d_in[6];
    const float* b_b   = (const float*)d_in[7];
    const float* W_out = (const float*)d_in[8];
    const float* b_out = (const float*)d_in[9];
    const float* trans = (const float*)d_in[10];
    const float* startt= (const float*)d_in[11];
    const float* stopt = (const float*)d_in[12];

    char* ws = (char*)d_ws;
    float* h_hist = (float*)(ws);                           //  67,108,864 B  [16384][1024]
    f16*   ehi    = (f16*)  (ws +  67108864ull);            //  16,777,216 B
    f16*   elo    = (f16*)  (ws +  83886080ull);            //  16,777,216 B
    f16*   wihhi  = (f16*)  (ws + 100663296ull);            //   4,194,304 B
    f16*   wihlo  = (f16*)  (ws + 104857600ull);
    f16*   whhhi  = (f16*)  (ws + 109051904ull);
    f16*   whhlo  = (f16*)  (ws + 113246208ull);
    unsigned* hx  = (unsigned*)(ws + 117440512ull);         //     262,144 B  [2][2][32][512]
    float* feats  = (float*)(ws + 117702656ull);            //   1,048,576 B

    // init exchange buffers: tag field (bits 17:16) = 3
    hipMemsetAsync(hx, 0xFF, 262144, stream);

    k_split4<<<dim3(512, 4), 256, 0, stream>>>(Wih_f, Wih_b, Whh_f, Whh_b,
                                               wihhi, wihlo, whhhi, whhlo);
    k_gather<<<16384, 256, 0, stream>>>(sentence, embedding, ehi, elo);

    k_rec<<<256, 512, 0, stream>>>(ehi, elo, whhhi, whhlo, wihhi, wihlo,
                                   b_f, b_b, hx, h_hist);

    k_feats<<<256, 256, 0, stream>>>(h_hist, W_out, b_out, feats);
    k_viterbi<<<32, 64, 0, stream>>>(feats, trans, startt, stopt, (int*)d_out);
}

// Round 15
// 2064.713 us; speedup vs baseline: 1.2092x; 1.0051x over previous
//
#include <hip/hip_runtime.h>
#include <stdint.h>

#define BATCH 32
#define SEQ   512
#define EDIM  512
#define HID   512            // per-direction hidden
#define NG    2048           // 4*HID gate rows
#define NTAG  16

typedef _Float16 f16;
typedef _Float16 f16x4 __attribute__((ext_vector_type(4)));
typedef _Float16 f16x8 __attribute__((ext_vector_type(8)));
typedef float    f32x4 __attribute__((ext_vector_type(4)));

#define LO_SCALE 2048.0f
#define LO_INV   (1.0f/2048.0f)

// ---------------- fused prep: weight limb-split (4 mats) + embedding gather +
// hx tag init, one launch. Blocks [0,2048): weights (512 per matrix, float4-
// vectorized); blocks [0,256) also init hx tags; blocks [2048,18432): gather.
__global__ __launch_bounds__(256) void k_prep(
    const float* __restrict__ s0, const float* __restrict__ s1,
    const float* __restrict__ s2, const float* __restrict__ s3,
    f16* __restrict__ wih_hi, f16* __restrict__ wih_lo,
    f16* __restrict__ whh_hi, f16* __restrict__ whh_lo,
    const int* __restrict__ sent, const float* __restrict__ emb,
    f16* __restrict__ ehi, f16* __restrict__ elo,
    unsigned* __restrict__ hx)
{
    const int b   = blockIdx.x;
    const int tid = threadIdx.x;
    if (b < 2048) {
        const int y = b >> 9;
        const float* src = (y == 0) ? s0 : (y == 1) ? s1 : (y == 2) ? s2 : s3;
        f16* hi = ((y < 2) ? wih_hi : whh_hi) + (size_t)(y & 1) * NG * EDIM;
        f16* lo = ((y < 2) ? wih_lo : whh_lo) + (size_t)(y & 1) * NG * EDIM;
        const int base = ((b & 511)*256 + tid) * 8;   // 512 blk x 256 thr x 8 = NG*EDIM
        #pragma unroll
        for (int j = 0; j < 8; j += 4) {
            float4 v = *(const float4*)(src + base + j);
            f16 h0 = (f16)v.x, h1 = (f16)v.y, h2 = (f16)v.z, h3 = (f16)v.w;
            f16x4 vh = {h0, h1, h2, h3};
            f16x4 vl = {(f16)((v.x - (float)h0) * LO_SCALE),
                        (f16)((v.y - (float)h1) * LO_SCALE),
                        (f16)((v.z - (float)h2) * LO_SCALE),
                        (f16)((v.w - (float)h3) * LO_SCALE)};
            *(f16x4*)(hi + base + j) = vh;
            *(f16x4*)(lo + base + j) = vl;
        }
        if (b < 256)                       // hx tag init: 65536 u32 total
            hx[b*256 + tid] = 0xFFFFFFFFu;
    } else {
        const int m = b - 2048;            // 0..16383 = batch*SEQ+s
        const int idx = sent[m];
        const float* src = emb + (size_t)idx * EDIM;
        const int k = tid * 2;
        float2 v = *(const float2*)(src + k);
        f16 h0 = (f16)v.x, h1 = (f16)v.y;
        ehi[(size_t)m*EDIM + k]     = h0;
        ehi[(size_t)m*EDIM + k + 1] = h1;
        elo[(size_t)m*EDIM + k]     = (f16)((v.x - (float)h0) * LO_SCALE);
        elo[(size_t)m*EDIM + k + 1] = (f16)((v.y - (float)h1) * LO_SCALE);
    }
}

__device__ __forceinline__ void gld16(const void* g, void* l) {
    __builtin_amdgcn_global_load_lds((const __attribute__((address_space(1))) uint32_t*)g,
                                     (__attribute__((address_space(3))) uint32_t*)l, 16, 0, 0);
}
__device__ __forceinline__ f32x4 mfma16(f16x8 a, f16x8 b, f32x4 c) {
    return __builtin_amdgcn_mfma_f32_16x16x32_f16(a, b, c, 0, 0, 0);
}

// ---------------- persistent fused BiLSTM (v15 = v14 recurrence, unchanged) -
// 256 WGs: dir(2) x mq(4, batch quarter = 8 rows) x chunk(32, 16 units).
// Proven 1910us recurrence: per-step gates = emb@Wih + h@Whh + bias; Wih/Whh
// limb B-fragments in registers; emb staged via global_load_lds under the
// poll; packed-u32 h exchange with 2-bit step tag (bits 17:16), per-packet
// pend-mask busy poll. Waves = (g 4 x kh 2); MFMA M=16 w/ row duplication.
__global__ __launch_bounds__(512, 1) void k_rec(
    const f16* __restrict__ ehi,  const f16* __restrict__ elo,   // [16384][512]
    const f16* __restrict__ Whhi, const f16* __restrict__ Whlo,  // [2][2048][512]
    const f16* __restrict__ Wihi, const f16* __restrict__ Wilo,  // [2][2048][512]
    const float* __restrict__ b_f, const float* __restrict__ b_b,
    unsigned* __restrict__ hx,                                   // [2][2][32][512] packed
    float* __restrict__ h_hist)                                  // [16384][1024]
{
    __shared__ char  hhiS[8192];              // h   hi plane [8 rows][64 x 16B] swizzled
    __shared__ char  hloS[8192];              // h   lo plane
    __shared__ char  ehiS[8192];              // emb hi plane (same layout)
    __shared__ char  eloS[8192];              // emb lo plane
    __shared__ float gbuf[2*4*16*17];         // [kh][g][row16][17] (rows 8-15 dup)

    const int wg    = blockIdx.x;
    const int dir   = wg >> 7;
    const int mq    = (wg >> 5) & 3;   // batch quarter
    const int chunk = wg & 31;
    const int u0    = chunk * 16;
    const int b0    = mq * 8;
    const int tid   = threadIdx.x;
    const int lane  = tid & 63;
    const int wave  = tid >> 6;
    const int g     = wave & 3;        // gate type
    const int kh    = wave >> 2;       // K half
    const int u     = lane & 15;
    const int q4    = lane >> 4;

    unsigned* hxd = hx + (size_t)dir * 2 * BATCH * HID;

    const int pbl = tid >> 4;          // cell: local batch row 0..7 (tid<128)
    const int pu  = tid & 15;          // cell: unit within chunk
    const char* hrowH = hhiS + (u & 7)*1024;   // A row = local batch row (u&7)
    const char* hrowL = hloS + (u & 7)*1024;
    const char* erowH = ehiS + (u & 7)*1024;
    const char* erowL = eloS + (u & 7)*1024;
    const int u7 = u & 7;

    // step-invariant Whh + Wih B-fragments -> registers (8 kt x hi/lo each)
    f16x8 bhv[8], blv[8], wbh[8], wbl[8];
    {
        const size_t row = (size_t)(dir*NG + g*512 + u0 + u) * EDIM;
        const f16* ph = Whhi + row + q4*8;
        const f16* pl = Whlo + row + q4*8;
        const f16* qh = Wihi + row + q4*8;
        const f16* ql = Wilo + row + q4*8;
        #pragma unroll
        for (int kt = 0; kt < 8; ++kt) {
            bhv[kt] = *(const f16x8*)(ph + (kh*8 + kt)*32);
            blv[kt] = *(const f16x8*)(pl + (kh*8 + kt)*32);
            wbh[kt] = *(const f16x8*)(qh + (kh*8 + kt)*32);
            wbl[kt] = *(const f16x8*)(ql + (kh*8 + kt)*32);
        }
    }

    // per-cell bias (4 gates), loaded once
    float bv[4];
    {
        const float* bias = dir ? b_b : b_f;
        #pragma unroll
        for (int gg = 0; gg < 4; ++gg) bv[gg] = bias[gg*512 + u0 + pu];
    }

    // emb staging: wave w fills plane row w (8 rows); lane l fetches logical
    // unit (l ^ w) so the LDS write is linear (gld_lds constraint).
    const int grow = b0 + wave;                // global batch row for this wave
    const int srcu = (lane ^ wave) * 8;        // f16 offset within source row

    float c = 0.0f;                   // cell state for (b0+pbl, u0+pu)

    for (int t = 0; t < SEQ; ++t) {
        const int s = dir ? (SEQ - 1 - t) : t;

        // ---- issue emb plane loads for step t (latency hides under poll) ----
        {
            size_t r0 = ((size_t)grow*SEQ + s) * EDIM + srcu;
            gld16(ehi + r0, ehiS + tid*16);
            gld16(elo + r0, eloS + tid*16);
        }

        // ---- fill h planes: poll packed exchange data for this step's tag ----
        if (t == 0) {
            #pragma unroll
            for (int i = 0; i < 2; ++i) {
                int q = i*512 + tid, row = q >> 7, kqq = (q & 127)*4;
                int off = row*1024 + ((kqq >> 3) ^ row)*16 + (kqq & 4)*2;
                *(uint2*)(hhiS + off) = (uint2){0u, 0u};
                *(uint2*)(hloS + off) = (uint2){0u, 0u};
            }
        } else {
            const unsigned tag32 = ((unsigned)((t - 1) >> 1) & 3u) << 16;
            const unsigned* hsrc = hxd + (size_t)(t & 1)*BATCH*HID + (size_t)b0*HID;
            unsigned pend = 0x3u;
            while (pend) {
                unsigned long long va[2], vb[2];
                #pragma unroll
                for (int i = 0; i < 2; ++i) {
                    if (pend & (1u << i)) {
                        int q = i*512 + tid;
                        const unsigned long long* p =
                            (const unsigned long long*)(hsrc + (q >> 7)*HID + (q & 127)*4);
                        va[i] = __hip_atomic_load(p,     __ATOMIC_RELAXED, __HIP_MEMORY_SCOPE_AGENT);
                        vb[i] = __hip_atomic_load(p + 1, __ATOMIC_RELAXED, __HIP_MEMORY_SCOPE_AGENT);
                    }
                }
                #pragma unroll
                for (int i = 0; i < 2; ++i) {
                    if (!(pend & (1u << i))) continue;
                    unsigned w0 = (unsigned)va[i], w1 = (unsigned)(va[i] >> 32);
                    unsigned w2 = (unsigned)vb[i], w3 = (unsigned)(vb[i] >> 32);
                    if ((((w0 ^ tag32) | (w1 ^ tag32) | (w2 ^ tag32) | (w3 ^ tag32)) & 0x30000u) != 0u)
                        continue;   // not all words carry this step's tag yet
                    unsigned hi01 = (w0 & 0xffffu) | (w1 << 16);
                    unsigned hi23 = (w2 & 0xffffu) | (w3 << 16);
                    unsigned lo01 = (w0 >> 16) | (w1 & 0xffff0000u);
                    unsigned lo23 = (w2 >> 16) | (w3 & 0xffff0000u);
                    int q = i*512 + tid, row = q >> 7, kqq = (q & 127)*4;
                    int off = row*1024 + ((kqq >> 3) ^ row)*16 + (kqq & 4)*2;
                    *(uint2*)(hhiS + off) = (uint2){hi01, hi23};
                    *(uint2*)(hloS + off) = (uint2){lo01, lo23};
                    pend &= ~(1u << i);
                }
            }
        }
        __syncthreads();                 // h planes + emb planes (vmcnt 0) ready

        // ---- MFMA: gates = emb@Wih + h@Whh for this wave's (g, kh) ----
        f32x4 aH = {0.f,0.f,0.f,0.f}, aM1 = aH, aM2 = aH;
        #pragma unroll
        for (int kt = 0; kt < 8; ++kt) {
            int off = (((kh*8 + kt)*4 + q4) ^ u7) * 16;
            f16x8 eh = *(const f16x8*)(erowH + off);
            f16x8 el = *(const f16x8*)(erowL + off);
            f16x8 ah = *(const f16x8*)(hrowH + off);
            f16x8 al = *(const f16x8*)(hrowL + off);
            aH  = mfma16(eh, wbh[kt], aH);
            aM1 = mfma16(eh, wbl[kt], aM1);
            aM2 = mfma16(el, wbh[kt], aM2);
            aH  = mfma16(ah, bhv[kt], aH);
            aM1 = mfma16(ah, blv[kt], aM1);
            aM2 = mfma16(al, bhv[kt], aM2);
        }
        #pragma unroll
        for (int j = 0; j < 4; ++j) {
            int row = q4*4 + j;                // 0..15 (rows 8-15 duplicate 0-7)
            gbuf[(kh*4 + g)*272 + row*17 + u] = aH[j] + (aM1[j] + aM2[j]) * LO_INV;
        }
        __syncthreads();                       // gbuf ready; plane reads done

        // ---- pointwise LSTM cell + packed tagged store (8 rows x 16 units) ----
        if (tid < 128) {
            float gs[4];
            #pragma unroll
            for (int gg = 0; gg < 4; ++gg)
                gs[gg] = gbuf[(0*4 + gg)*272 + pbl*17 + pu]
                       + gbuf[(1*4 + gg)*272 + pbl*17 + pu] + bv[gg];
            float si = 1.0f / (1.0f + __expf(-gs[0]));
            float sf = 1.0f / (1.0f + __expf(-gs[1]));
            float tg = 1.0f - 2.0f / (__expf(2.0f*gs[2]) + 1.0f);
            float so = 1.0f / (1.0f + __expf(-gs[3]));
            c = sf * c + si * tg;
            float hval = so * (1.0f - 2.0f / (__expf(2.0f*c) + 1.0f));
            f16 hh = (f16)hval;
            f16 hl = (f16)((hval - (float)hh) * LO_SCALE);
            unsigned packed = (unsigned)__builtin_bit_cast(unsigned short, hh)
                            | ((unsigned)__builtin_bit_cast(unsigned short, hl) << 16);
            packed = (packed & ~0x30000u) | ((((unsigned)t >> 1) & 3u) << 16);
            int b = b0 + pbl;
            unsigned* hdst = hxd + (size_t)((t + 1) & 1)*BATCH*HID + b*HID + u0 + pu;
            __hip_atomic_store(hdst, packed, __ATOMIC_RELAXED, __HIP_MEMORY_SCOPE_AGENT);
            // h_hist off the critical path; non-temporal (keep L2 clean)
            __builtin_nontemporal_store(hval,
                h_hist + ((size_t)b*SEQ + s)*1024 + dir*HID + u0 + pu);
        }
    }
}

// ---------------- output projection: feats = H @ W_out^T + b_out ------------
// 256 blocks x 64 rows: Wout LDS staging amortized 16x.
__global__ __launch_bounds__(256) void k_feats(
    const float* __restrict__ H,      // [16384][1024]
    const float* __restrict__ Wout,   // [16][1024]
    const float* __restrict__ bout,   // [16]
    float* __restrict__ feats)        // [16384][16]
{
    __shared__ float Wt[1024][16];    // 64 KiB, transposed
    int tid = threadIdx.x;
    for (int i = tid; i < 16384; i += 256)
        Wt[i & 1023][i >> 10] = Wout[i];   // coalesced global read
    __syncthreads();
    int wave = tid >> 6, lane = tid & 63;
    float bo[16];
    #pragma unroll
    for (int tg = 0; tg < 16; ++tg) bo[tg] = bout[tg];
    for (int r = 0; r < 16; ++r) {
        int row = blockIdx.x * 64 + wave * 16 + r;
        const float* hrow = H + (size_t)row * 1024;
        float acc[16];
        #pragma unroll
        for (int t = 0; t < 16; ++t) acc[t] = 0.f;
        #pragma unroll
        for (int cc = 0; cc < 4; ++cc) {
            float4 hv = *(const float4*)(hrow + cc*256 + lane*4);
            #pragma unroll
            for (int j = 0; j < 4; ++j) {
                int k = cc*256 + lane*4 + j;
                float h = (&hv.x)[j];
                #pragma unroll
                for (int tg = 0; tg < 16; ++tg) acc[tg] += h * Wt[k][tg];
            }
        }
        #pragma unroll
        for (int off = 32; off >= 1; off >>= 1) {
            #pragma unroll
            for (int tg = 0; tg < 16; ++tg) acc[tg] += __shfl_xor(acc[tg], off);
        }
        if (lane == 0) {
            #pragma unroll
            for (int tg = 0; tg < 16; ++tg)
                feats[(size_t)row*16 + tg] = acc[tg] + bo[tg];
        }
    }
}

// ---------------- Viterbi + backtrace (one wave per batch, LDS-staged) ------
__global__ __launch_bounds__(64) void k_viterbi(
    const float* __restrict__ feats,   // [32][512][16]
    const float* __restrict__ trans,   // [16][16] trans[prev][cur]
    const float* __restrict__ startt, const float* __restrict__ stopt,
    int* __restrict__ out)             // [32][512]
{
    __shared__ float fs[SEQ*NTAG];     // 32 KiB: whole feats row
    __shared__ unsigned char bp[511*16];
    int b = blockIdx.x;
    int lane = threadIdx.x;
    // stage feats row into LDS (coalesced float4)
    {
        const float4* src = (const float4*)(feats + (size_t)b * SEQ * NTAG);
        float4* dst = (float4*)fs;
        for (int i = lane; i < SEQ*NTAG/4; i += 64) dst[i] = src[i];
    }
    int cur = lane & 15;
    int q   = lane >> 4;
    float tr[4];
    #pragma unroll
    for (int i = 0; i < 4; ++i) tr[i] = trans[(q*4 + i)*16 + cur];
    __syncthreads();
    float v = fs[cur] + startt[cur];
    for (int s = 1; s < SEQ; ++s) {
        float best = -1e30f; int bi = 0;
        #pragma unroll
        for (int i = 0; i < 4; ++i) {
            float pv = __shfl(v, q*4 + i);
            float sc = pv + tr[i];
            if (sc > best) { best = sc; bi = q*4 + i; }   // first-max within quarter
        }
        #pragma unroll
        for (int off = 16; off <= 32; off <<= 1) {
            float ob = __shfl_xor(best, off);
            int   oi = __shfl_xor(bi, off);
            if (ob > best || (ob == best && oi < bi)) { best = ob; bi = oi; }
        }
        if (lane < 16) bp[(s - 1)*16 + cur] = (unsigned char)bi;
        v = best + fs[s*16 + cur];
    }
    float sc = v + stopt[cur];
    int bc = cur;
    #pragma unroll
    for (int off = 1; off <= 32; off <<= 1) {
        float os = __shfl_xor(sc, off);
        int   oc = __shfl_xor(bc, off);
        if (os > sc || (os == sc && oc < bc)) { sc = os; bc = oc; }
    }
    __syncthreads();
    if (lane == 0) {
        int curt = bc;
        out[b*SEQ + SEQ - 1] = curt;
        for (int s2 = SEQ - 2; s2 >= 0; --s2) {
            curt = bp[s2*16 + curt];
            out[b*SEQ + s2] = curt;
        }
    }
}

// ---------------- launch ----------------------------------------------------
extern "C" void kernel_launch(void* const* d_in, const int* in_sizes, int n_in,
                              void* d_out, int out_size, void* d_ws, size_t ws_size,
                              hipStream_t stream) {
    (void)in_sizes; (void)n_in; (void)out_size; (void)ws_size;
    const int*   sentence  = (const int*)  d_in[0];
    const float* embedding = (const float*)d_in[1];
    const float* Wih_f = (const float*)d_in[2];
    const float* Whh_f = (const float*)d_in[3];
    const float* b_f   = (const float*)d_in[4];
    const float* Wih_b = (const float*)d_in[5];
    const float* Whh_b = (const float*)d_in[6];
    const float* b_b   = (const float*)d_in[7];
    const float* W_out = (const float*)d_in[8];
    const float* b_out = (const float*)d_in[9];
    const float* trans = (const float*)d_in[10];
    const float* startt= (const float*)d_in[11];
    const float* stopt = (const float*)d_in[12];

    char* ws = (char*)d_ws;
    float* h_hist = (float*)(ws);                           //  67,108,864 B  [16384][1024]
    f16*   ehi    = (f16*)  (ws +  67108864ull);            //  16,777,216 B
    f16*   elo    = (f16*)  (ws +  83886080ull);            //  16,777,216 B
    f16*   wihhi  = (f16*)  (ws + 100663296ull);            //   4,194,304 B
    f16*   wihlo  = (f16*)  (ws + 104857600ull);
    f16*   whhhi  = (f16*)  (ws + 109051904ull);
    f16*   whhlo  = (f16*)  (ws + 113246208ull);
    unsigned* hx  = (unsigned*)(ws + 117440512ull);         //     262,144 B  [2][2][32][512]
    float* feats  = (float*)(ws + 117702656ull);            //   1,048,576 B

    // single fused prep launch: weight limb-split + gather + hx tag init
    k_prep<<<18432, 256, 0, stream>>>(Wih_f, Wih_b, Whh_f, Whh_b,
                                      wihhi, wihlo, whhhi, whhlo,
                                      sentence, embedding, ehi, elo, hx);

    k_rec<<<256, 512, 0, stream>>>(ehi, elo, whhhi, whhlo, wihhi, wihlo,
                                   b_f, b_b, hx, h_hist);

    k_feats<<<256, 256, 0, stream>>>(h_hist, W_out, b_out, feats);
    k_viterbi<<<32, 64, 0, stream>>>(feats, trans, startt, stopt, (int*)d_out);
}